// Round 2
// baseline (1104.688 us; speedup 1.0000x reference)
//
#include <hip/hip_runtime.h>
#include <hip/hip_bf16.h>

// DQTLinear: C[M][N] = x[M][K] @ W^T,  W[n][k] = ternary[n][k] * scales[n*32 + k/128]
// M=8192 (2*4096), N=4096, K=4096, group size 128 along K.
// ternary arrives as int32 (harness upcasts integer inputs: "integer -> const int*").
// bf16 MFMA path: x -> bf16, W -> bf16(t*s) fused at staging (bf16-grade threshold).

#define M_DIM 8192
#define N_DIM 4096
#define K_DIM 4096
#define NGRP  32      // scale groups per output row = K/128
#define BM 128
#define BN 128
#define BK 64
#define NPAIR 32      // K / (2*BK)

typedef float f32x4 __attribute__((ext_vector_type(4)));
typedef short bf16x8 __attribute__((ext_vector_type(8)));

struct StageRegs { float4 a0, a1, a2, a3; int4 b0, b1, b2, b3; float s; };

__device__ __forceinline__ void issue_loads(StageRegs& r,
    const float* __restrict__ X, const int* __restrict__ T,
    const float* __restrict__ S,
    int arow_g, int brow_g, int kt, int kq) {
  const int kbase = kt * BK;
  const float4* pa = reinterpret_cast<const float4*>(X + (size_t)arow_g * K_DIM + kbase + kq * 16);
  r.a0 = pa[0]; r.a1 = pa[1]; r.a2 = pa[2]; r.a3 = pa[3];
  const int4* pb = reinterpret_cast<const int4*>(T + (size_t)brow_g * K_DIM + kbase + kq * 16);
  r.b0 = pb[0]; r.b1 = pb[1]; r.b2 = pb[2]; r.b3 = pb[3];
  // one scale per thread per k-tile: this thread's 16 k-columns lie in group kt/2
  r.s = S[(size_t)brow_g * NGRP + (kt >> 1)];
}

// LDS planes: [128 rows][64 k] bf16 (128 B/row), XOR-swizzled: byte ^= (row&7)<<4.
__device__ __forceinline__ void stage_to_lds(const StageRegs& r,
    char* __restrict__ als, char* __restrict__ bls, int rrow, int kq) {
  const int xorv = (rrow & 7) << 4;
  const int base = rrow * 128 + kq * 32;
  const float* xf = (const float*)&r.a0;
  const int*   wi = (const int*)&r.b0;
  bf16x8 av0, av1, wv0, wv1;
#pragma unroll
  for (int e = 0; e < 8; ++e) {
    av0[e] = __builtin_bit_cast(short, __float2bfloat16(xf[e]));
    av1[e] = __builtin_bit_cast(short, __float2bfloat16(xf[8 + e]));
    wv0[e] = __builtin_bit_cast(short, __float2bfloat16((float)wi[e] * r.s));
    wv1[e] = __builtin_bit_cast(short, __float2bfloat16((float)wi[8 + e] * r.s));
  }
  *(bf16x8*)(als + ((base     ) ^ xorv)) = av0;
  *(bf16x8*)(als + ((base + 16) ^ xorv)) = av1;
  *(bf16x8*)(bls + ((base     ) ^ xorv)) = wv0;
  *(bf16x8*)(bls + ((base + 16) ^ xorv)) = wv1;
}

__device__ __forceinline__ void compute_tile(const char* __restrict__ als,
    const char* __restrict__ bls,
    int lane, int wr, int wc, f32x4 (&acc)[4][2]) {
  const int lm = lane & 15;
  const int lk = (lane >> 4) << 4;        // byte offset of lane's 8-k slice
  const int xorv = (lm & 7) << 4;         // row&7 == lm&7 (row bases are multiples of 16)
#pragma unroll
  for (int ks = 0; ks < 2; ++ks) {
    const int kb = ks * 64 + lk;
    bf16x8 ah[4], bq[2];
#pragma unroll
    for (int i = 0; i < 4; ++i)
      ah[i] = *(const bf16x8*)(als + (((wr * 64 + i * 16 + lm) * 128 + kb) ^ xorv));
#pragma unroll
    for (int j = 0; j < 2; ++j)
      bq[j] = *(const bf16x8*)(bls + (((wc * 32 + j * 16 + lm) * 128 + kb) ^ xorv));
#pragma unroll
    for (int i = 0; i < 4; ++i)
#pragma unroll
      for (int j = 0; j < 2; ++j)
        acc[i][j] = __builtin_amdgcn_mfma_f32_16x16x32_bf16(ah[i], bq[j], acc[i][j], 0, 0, 0);
  }
}

__global__ __launch_bounds__(512, 2) void dqt_gemm(
    const float* __restrict__ X, const int* __restrict__ T,
    const float* __restrict__ S, float* __restrict__ C) {
  // Bijective chunked XCD swizzle (2048 = 8*256): XCD x gets a contiguous wg range;
  // bm-major so an XCD's resident blocks share one A row-panel in its L2.
  int b = blockIdx.x;                 // 2048 blocks
  int wg = (b & 7) * 256 + (b >> 3);
  int bm = wg >> 5;                   // 64 row-blocks
  int bn = wg & 31;                   // 32 col-blocks
  const int row0 = bm * BM;
  const int col0 = bn * BN;

  const int tid = threadIdx.x;
  const int lane = tid & 63;
  const int wid = tid >> 6;           // 8 waves
  const int wr = wid >> 2;            // 2 wave-rows (64 M each)
  const int wc = wid & 3;             // 4 wave-cols (32 N each)

  __shared__ __align__(16) short lds_a[BM * BK];
  __shared__ __align__(16) short lds_b[BN * BK];
  char* als = (char*)lds_a;
  char* bls = (char*)lds_b;

  const int srow = tid >> 2;          // staging row 0..127
  const int kq = tid & 3;             // staging k-quarter
  const int arow_g = row0 + srow;
  const int brow_g = col0 + srow;

  f32x4 acc[4][2] = {};

  StageRegs rA, rB;
  issue_loads(rA, X, T, S, arow_g, brow_g, 0, kq);

#pragma unroll 1
  for (int p = 0; p < NPAIR; ++p) {
    // ---- even K-tile (kt = 2p) ----
    stage_to_lds(rA, als, bls, srow, kq);
    __syncthreads();
    issue_loads(rB, X, T, S, arow_g, brow_g, 2 * p + 1, kq);
    compute_tile(als, bls, lane, wr, wc, acc);
    __syncthreads();
    // ---- odd K-tile (kt = 2p+1) ----
    stage_to_lds(rB, als, bls, srow, kq);
    __syncthreads();
    if (p + 1 < NPAIR)
      issue_loads(rA, X, T, S, arow_g, brow_g, 2 * p + 2, kq);
    compute_tile(als, bls, lane, wr, wc, acc);
    __syncthreads();
  }

  // Epilogue: C/D layout col=lane&15 (N side), row=(lane>>4)*4+q (M side)  [m89-verified]
  const int crow0 = row0 + wr * 64 + ((lane >> 4) << 2);
#pragma unroll
  for (int i = 0; i < 4; ++i) {
#pragma unroll
    for (int j = 0; j < 2; ++j) {
      int colc = col0 + wc * 32 + j * 16 + (lane & 15);
#pragma unroll
      for (int q = 0; q < 4; ++q) {
        int rowc = crow0 + i * 16 + q;
        C[(size_t)rowc * N_DIM + colc] = acc[i][j][q];
      }
    }
  }
}

extern "C" void kernel_launch(void* const* d_in, const int* in_sizes, int n_in,
                              void* d_out, int out_size, void* d_ws, size_t ws_size,
                              hipStream_t stream) {
  const float* X = (const float*)d_in[0];
  const int* T = (const int*)d_in[1];       // harness upcasts int8 -> int32
  const float* S = (const float*)d_in[2];
  float* C = (float*)d_out;
  dim3 grid((M_DIM / BM) * (N_DIM / BN));   // 2048
  dim3 block(512);
  dqt_gemm<<<grid, block, 0, stream>>>(X, T, S, C);
}

// Round 3
// 498.031 us; speedup vs baseline: 2.2181x; 2.2181x over previous
//
#include <hip/hip_runtime.h>
#include <hip/hip_bf16.h>

// DQTLinear: C[M][N] = x[M][K] @ W^T, W[n][k] = ternary[n][k]*scales[n*32+k/128]
// M=8192, N=4096, K=4096. ternary arrives as int32 (harness upcasts int inputs).
// R3: prepass dequant (X->bf16, W->bf16) into ws in K-tiled swizzled layout,
// then 256x256 8-phase counted-vmcnt MFMA GEMM (T1+T2+T3+T4+T5).

#define M_DIM 8192
#define N_DIM 4096
#define K_DIM 4096
#define NGRP 32

#define BM 256
#define BN 256
#define NT 64              // K tiles of 64
#define SLOT_B 16384       // 256 rows x 32 K x 2B (one half-tile)
#define TILE_B 32768       // per matrix per K-tile (2 half-tiles)
#define A_BYTES (32ull * NT * TILE_B)   // 64 MiB
#define B_BYTES (16ull * NT * TILE_B)   // 32 MiB

typedef float f32x4 __attribute__((ext_vector_type(4)));
typedef short bf16x8 __attribute__((ext_vector_type(8)));

// ---------------- prepass: X (fp32) -> A' bf16, tiled+swizzled ----------------
// A' chunk layout: slot = (bm*64+kt)*2+kk ; within slot: [r 0..255][ch 0..3][16B]
// stored data(r, ch) = X[bm*256+r][kt*64+kk*32 + (ch ^ ((r>>1)&3))*8 + e]
__global__ void prep_a(const float* __restrict__ X, char* __restrict__ A) {
  const int total = 32 * 128 * 1024;  // 4194304 16B-chunks
  for (int c = blockIdx.x * blockDim.x + threadIdx.x; c < total;
       c += gridDim.x * blockDim.x) {
    int within = c & 1023;
    int slot = c >> 10;
    int r = within >> 2, ch = within & 3;
    int kk = slot & 1, kt = (slot >> 1) & 63, bm = slot >> 7;
    int gr = bm * BM + r;
    int kb = kt * 64 + kk * 32 + ((ch ^ ((r >> 1) & 3)) << 3);
    const float4* p = reinterpret_cast<const float4*>(X + (size_t)gr * K_DIM + kb);
    float4 u = p[0], v = p[1];
    bf16x8 o;
    o[0] = __builtin_bit_cast(short, __float2bfloat16(u.x));
    o[1] = __builtin_bit_cast(short, __float2bfloat16(u.y));
    o[2] = __builtin_bit_cast(short, __float2bfloat16(u.z));
    o[3] = __builtin_bit_cast(short, __float2bfloat16(u.w));
    o[4] = __builtin_bit_cast(short, __float2bfloat16(v.x));
    o[5] = __builtin_bit_cast(short, __float2bfloat16(v.y));
    o[6] = __builtin_bit_cast(short, __float2bfloat16(v.z));
    o[7] = __builtin_bit_cast(short, __float2bfloat16(v.w));
    *reinterpret_cast<bf16x8*>(A + (size_t)c * 16) = o;
  }
}

// ---------------- prepass: ternary(int32)*scale -> B' bf16 ----------------
__global__ void prep_b(const int* __restrict__ T, const float* __restrict__ S,
                       char* __restrict__ B) {
  const int total = 16 * 128 * 1024;  // 2097152 chunks
  for (int c = blockIdx.x * blockDim.x + threadIdx.x; c < total;
       c += gridDim.x * blockDim.x) {
    int within = c & 1023;
    int slot = c >> 10;
    int r = within >> 2, ch = within & 3;
    int kk = slot & 1, kt = (slot >> 1) & 63, bn = slot >> 7;
    int gn = bn * BN + r;
    int kb = kt * 64 + kk * 32 + ((ch ^ ((r >> 1) & 3)) << 3);
    float s = S[(size_t)gn * NGRP + (kt >> 1)];
    const int4* p = reinterpret_cast<const int4*>(T + (size_t)gn * K_DIM + kb);
    int4 u = p[0], v = p[1];
    bf16x8 o;
    o[0] = __builtin_bit_cast(short, __float2bfloat16((float)u.x * s));
    o[1] = __builtin_bit_cast(short, __float2bfloat16((float)u.y * s));
    o[2] = __builtin_bit_cast(short, __float2bfloat16((float)u.z * s));
    o[3] = __builtin_bit_cast(short, __float2bfloat16((float)u.w * s));
    o[4] = __builtin_bit_cast(short, __float2bfloat16((float)v.x * s));
    o[5] = __builtin_bit_cast(short, __float2bfloat16((float)v.y * s));
    o[6] = __builtin_bit_cast(short, __float2bfloat16((float)v.z * s));
    o[7] = __builtin_bit_cast(short, __float2bfloat16((float)v.w * s));
    *reinterpret_cast<bf16x8*>(B + (size_t)c * 16) = o;
  }
}

// ---------------- main GEMM: 256x256, 8 waves, 8-phase counted vmcnt ----------------
__device__ __forceinline__ void gload16(const char* g, const char* l) {
  __builtin_amdgcn_global_load_lds(
      (const __attribute__((address_space(1))) void*)g,
      (__attribute__((address_space(3))) void*)l, 16, 0, 0);
}

__global__ __launch_bounds__(512, 2) void dqt_gemm8(
    const char* __restrict__ Aws, const char* __restrict__ Bws,
    float* __restrict__ C) {
  __shared__ __align__(16) char lds[131072];  // 2 bufs x 4 slots x 16KiB
  // buf b at b*65536; slots: A_Klo +0, A_Khi +16384, B_Klo +32768, B_Khi +49152

  // T1: chunked XCD swizzle; per XCD 4 bm x 16 bn, bn fast
  int b = blockIdx.x;             // 512
  int xcd = b & 7, idx = b >> 3;
  int bm = xcd * 4 + (idx >> 4);  // 0..31
  int bn = idx & 15;              // 0..15

  const int tid = threadIdx.x;
  const int lane = tid & 63;
  const int wid = tid >> 6;       // 8 waves
  const int wr = wid >> 2;        // M half
  const int wc = wid & 3;         // N quarter (64 cols)
  const int lm = lane & 15;
  const int lg = lane >> 4;

  // staging source (per-lane) and LDS wave base (wave-uniform)
  const char* pA = Aws + ((size_t)bm << 21) + wid * 2048 + lane * 16;
  const char* pB = Bws + ((size_t)bn << 21) + wid * 2048 + lane * 16;
  const int sbase = wid * 2048;

#define STAGE(dstoff, src)                              \
  do {                                                  \
    gload16((src), lds + (dstoff) + sbase);             \
    gload16((src) + 1024, lds + (dstoff) + sbase + 1024); \
  } while (0)

  // ds_read frag offsets (T2 swizzle: phys chunk = lg ^ ((lm>>1)&3))
  const int pc = (lg ^ ((lm >> 1) & 3)) * 16;
  const int aoff0 = (wr * 128 + lm) * 64 + pc;          // + m*1024 + kk*16384
  const int boff0 = 32768 + (wc * 64 + lm) * 64 + pc;   // + n*1024 + kk*16384

  f32x4 acc[8][4] = {};
  bf16x8 ah[4], bq[4];

  // Prologue: tile0 full (8 loads) + tile1 Klo pair (4 loads); retire tile0.
  STAGE(0, pA);                      // buf0 A-Klo  (tile0)
  STAGE(16384, pA + 16384);          // buf0 A-Khi
  STAGE(32768, pB);                  // buf0 B-Klo
  STAGE(49152, pB + 16384);          // buf0 B-Khi
  STAGE(65536, pA + 32768);          // buf1 A-Klo  (tile1)
  STAGE(65536 + 32768, pB + 32768);  // buf1 B-Klo
  asm volatile("s_waitcnt vmcnt(4)" ::: "memory");
  __builtin_amdgcn_s_barrier();

#pragma unroll 1
  for (int t = 0; t < NT; ++t) {
    const int cb = (t & 1) << 16;
    const int nb = (~t & 1) << 16;
    const char* sA1 = pA + (t + 1) * TILE_B;
    const char* sB1 = pB + (t + 1) * TILE_B;
    const char* sA2 = pA + (t + 2) * TILE_B;
    const char* sB2 = pB + (t + 2) * TILE_B;

    // ---- ph1: kk0, m0-3 (8 ds_read) ; stage next-tile Khi pair ----
#pragma unroll
    for (int m = 0; m < 4; ++m)
      ah[m] = *(const bf16x8*)(lds + cb + aoff0 + m * 1024);
#pragma unroll
    for (int n = 0; n < 4; ++n)
      bq[n] = *(const bf16x8*)(lds + cb + boff0 + n * 1024);
    if (t + 1 < NT) {
      STAGE(nb + 16384, sA1 + 16384);   // A-Khi(t+1)
      STAGE(nb + 49152, sB1 + 16384);   // B-Khi(t+1)
    }
    __builtin_amdgcn_s_barrier();
    __builtin_amdgcn_s_setprio(1);
#pragma unroll
    for (int m = 0; m < 4; ++m)
#pragma unroll
      for (int n = 0; n < 4; ++n)
        acc[m][n] = __builtin_amdgcn_mfma_f32_16x16x32_bf16(ah[m], bq[n], acc[m][n], 0, 0, 0);
    __builtin_amdgcn_s_setprio(0);
    __builtin_amdgcn_s_barrier();

    // ---- ph2: kk0, m4-7 (4 ds_read, B reuse) ----
#pragma unroll
    for (int m = 0; m < 4; ++m)
      ah[m] = *(const bf16x8*)(lds + cb + aoff0 + (m + 4) * 1024);
    __builtin_amdgcn_s_barrier();
    __builtin_amdgcn_s_setprio(1);
#pragma unroll
    for (int m = 0; m < 4; ++m)
#pragma unroll
      for (int n = 0; n < 4; ++n)
        acc[m + 4][n] = __builtin_amdgcn_mfma_f32_16x16x32_bf16(ah[m], bq[n], acc[m + 4][n], 0, 0, 0);
    __builtin_amdgcn_s_setprio(0);
    __builtin_amdgcn_s_barrier();

    // ---- ph3: kk1, m0-3 (8 ds_read) ; stage t+2 A-Klo (Klo last read in ph2) ----
#pragma unroll
    for (int m = 0; m < 4; ++m)
      ah[m] = *(const bf16x8*)(lds + cb + 16384 + aoff0 + m * 1024);
#pragma unroll
    for (int n = 0; n < 4; ++n)
      bq[n] = *(const bf16x8*)(lds + cb + 16384 + boff0 + n * 1024);
    if (t + 2 < NT) STAGE(cb + 0, sA2);
    __builtin_amdgcn_s_barrier();
    __builtin_amdgcn_s_setprio(1);
#pragma unroll
    for (int m = 0; m < 4; ++m)
#pragma unroll
      for (int n = 0; n < 4; ++n)
        acc[m][n] = __builtin_amdgcn_mfma_f32_16x16x32_bf16(ah[m], bq[n], acc[m][n], 0, 0, 0);
    __builtin_amdgcn_s_setprio(0);
    __builtin_amdgcn_s_barrier();

    // ---- ph4: kk1, m4-7 (4 ds_read) ; stage t+2 B-Klo ; counted vmcnt ----
#pragma unroll
    for (int m = 0; m < 4; ++m)
      ah[m] = *(const bf16x8*)(lds + cb + 16384 + aoff0 + (m + 4) * 1024);
    if (t + 2 < NT) STAGE(cb + 32768, sB2);
    __builtin_amdgcn_s_barrier();
    __builtin_amdgcn_s_setprio(1);
#pragma unroll
    for (int m = 0; m < 4; ++m)
#pragma unroll
      for (int n = 0; n < 4; ++n)
        acc[m + 4][n] = __builtin_amdgcn_mfma_f32_16x16x32_bf16(ah[m], bq[n], acc[m + 4][n], 0, 0, 0);
    __builtin_amdgcn_s_setprio(0);
    // retire everything through this tile's ph1 issues (= all of tile t+1's data)
    if (t < NT - 3)
      asm volatile("s_waitcnt vmcnt(4)" ::: "memory");
    else
      asm volatile("s_waitcnt vmcnt(0)" ::: "memory");
    __builtin_amdgcn_s_barrier();
  }

  // Epilogue: C/D map col=lane&15 (N), row=lg*4+q (M)
  const int row0 = bm * BM + wr * 128 + lg * 4;
  const int col0 = bn * BN + wc * 64 + lm;
#pragma unroll
  for (int m = 0; m < 8; ++m)
#pragma unroll
    for (int n = 0; n < 4; ++n) {
      float* cp = C + (size_t)(row0 + m * 16) * N_DIM + col0 + n * 16;
#pragma unroll
      for (int q = 0; q < 4; ++q)
        cp[(size_t)q * N_DIM] = acc[m][n][q];
    }
#undef STAGE
}

// ---------------- fallback (proven R2 kernel) if ws too small ----------------
typedef short bf16x8_ __attribute__((ext_vector_type(8)));
struct StageRegs { float4 a0, a1, a2, a3; int4 b0, b1, b2, b3; float s; };

__device__ __forceinline__ void fb_issue(StageRegs& r, const float* __restrict__ X,
    const int* __restrict__ T, const float* __restrict__ S,
    int arow_g, int brow_g, int kt, int kq) {
  const int kbase = kt * 64;
  const float4* pa = reinterpret_cast<const float4*>(X + (size_t)arow_g * K_DIM + kbase + kq * 16);
  r.a0 = pa[0]; r.a1 = pa[1]; r.a2 = pa[2]; r.a3 = pa[3];
  const int4* pb = reinterpret_cast<const int4*>(T + (size_t)brow_g * K_DIM + kbase + kq * 16);
  r.b0 = pb[0]; r.b1 = pb[1]; r.b2 = pb[2]; r.b3 = pb[3];
  r.s = S[(size_t)brow_g * NGRP + (kt >> 1)];
}
__device__ __forceinline__ void fb_stage(const StageRegs& r, char* als, char* bls,
                                         int rrow, int kq) {
  const int xorv = (rrow & 7) << 4;
  const int base = rrow * 128 + kq * 32;
  const float* xf = (const float*)&r.a0;
  const int* wi = (const int*)&r.b0;
  bf16x8_ av0, av1, wv0, wv1;
#pragma unroll
  for (int e = 0; e < 8; ++e) {
    av0[e] = __builtin_bit_cast(short, __float2bfloat16(xf[e]));
    av1[e] = __builtin_bit_cast(short, __float2bfloat16(xf[8 + e]));
    wv0[e] = __builtin_bit_cast(short, __float2bfloat16((float)wi[e] * r.s));
    wv1[e] = __builtin_bit_cast(short, __float2bfloat16((float)wi[8 + e] * r.s));
  }
  *(bf16x8_*)(als + ((base) ^ xorv)) = av0;
  *(bf16x8_*)(als + ((base + 16) ^ xorv)) = av1;
  *(bf16x8_*)(bls + ((base) ^ xorv)) = wv0;
  *(bf16x8_*)(bls + ((base + 16) ^ xorv)) = wv1;
}
__device__ __forceinline__ void fb_compute(const char* als, const char* bls,
    int lane, int wr, int wc, f32x4 (&acc)[4][2]) {
  const int lm = lane & 15;
  const int lk = (lane >> 4) << 4;
  const int xorv = (lm & 7) << 4;
#pragma unroll
  for (int ks = 0; ks < 2; ++ks) {
    const int kb = ks * 64 + lk;
    bf16x8_ ah[4], bq[2];
#pragma unroll
    for (int i = 0; i < 4; ++i)
      ah[i] = *(const bf16x8_*)(als + (((wr * 64 + i * 16 + lm) * 128 + kb) ^ xorv));
#pragma unroll
    for (int j = 0; j < 2; ++j)
      bq[j] = *(const bf16x8_*)(bls + (((wc * 32 + j * 16 + lm) * 128 + kb) ^ xorv));
#pragma unroll
    for (int i = 0; i < 4; ++i)
#pragma unroll
      for (int j = 0; j < 2; ++j)
        acc[i][j] = __builtin_amdgcn_mfma_f32_16x16x32_bf16(ah[i], bq[j], acc[i][j], 0, 0, 0);
  }
}
__global__ __launch_bounds__(512, 2) void dqt_gemm_fb(
    const float* __restrict__ X, const int* __restrict__ T,
    const float* __restrict__ S, float* __restrict__ C) {
  int b = blockIdx.x;
  int wg = (b & 7) * 256 + (b >> 3);
  int bm = wg >> 5, bn = wg & 31;
  const int row0 = bm * 128, col0 = bn * 128;
  const int tid = threadIdx.x, lane = tid & 63, wid = tid >> 6;
  const int wr = wid >> 2, wc = wid & 3;
  __shared__ __align__(16) short lds_a[128 * 64];
  __shared__ __align__(16) short lds_b[128 * 64];
  char* als = (char*)lds_a;
  char* bls = (char*)lds_b;
  const int srow = tid >> 2, kq = tid & 3;
  const int arow_g = row0 + srow, brow_g = col0 + srow;
  f32x4 acc[4][2] = {};
  StageRegs rA, rB;
  fb_issue(rA, X, T, S, arow_g, brow_g, 0, kq);
#pragma unroll 1
  for (int p = 0; p < 32; ++p) {
    fb_stage(rA, als, bls, srow, kq);
    __syncthreads();
    fb_issue(rB, X, T, S, arow_g, brow_g, 2 * p + 1, kq);
    fb_compute(als, bls, lane, wr, wc, acc);
    __syncthreads();
    fb_stage(rB, als, bls, srow, kq);
    __syncthreads();
    if (p + 1 < 32) fb_issue(rA, X, T, S, arow_g, brow_g, 2 * p + 2, kq);
    fb_compute(als, bls, lane, wr, wc, acc);
    __syncthreads();
  }
  const int crow0 = row0 + wr * 64 + ((lane >> 4) << 2);
#pragma unroll
  for (int i = 0; i < 4; ++i)
#pragma unroll
    for (int j = 0; j < 2; ++j) {
      int colc = col0 + wc * 32 + j * 16 + (lane & 15);
#pragma unroll
      for (int q = 0; q < 4; ++q)
        C[(size_t)(crow0 + i * 16 + q) * N_DIM + colc] = acc[i][j][q];
    }
}

extern "C" void kernel_launch(void* const* d_in, const int* in_sizes, int n_in,
                              void* d_out, int out_size, void* d_ws, size_t ws_size,
                              hipStream_t stream) {
  const float* X = (const float*)d_in[0];
  const int* T = (const int*)d_in[1];
  const float* S = (const float*)d_in[2];
  float* C = (float*)d_out;
  if (ws_size >= A_BYTES + B_BYTES) {
    char* Aws = (char*)d_ws;
    char* Bws = (char*)d_ws + A_BYTES;
    prep_a<<<2048, 256, 0, stream>>>(X, Aws);
    prep_b<<<2048, 256, 0, stream>>>(T, S, Bws);
    dqt_gemm8<<<512, 512, 0, stream>>>(Aws, Bws, C);
  } else {
    dqt_gemm_fb<<<2048, 512, 0, stream>>>(X, T, S, C);
  }
}